// Round 12
// baseline (126.765 us; speedup 1.0000x reference)
//
#include <hip/hip_runtime.h>

#define T_LEN 2048
#define CH 64
#define NH 8
#define STILE 64      // keys per tile (split 2 ways across ws)
#define TTILE 256     // queries per block (split 8 ways across wt)
#define WT 32         // queries per wave
#define NIT (T_LEN / STILE)   // 32 tiles, processed in 16 pairs
#define KSZ (STILE * CH)      // k_hi elems per buffer (64x64, no pad, XOR-swizzled)
#define CS 72         // v_s row stride (bf16), 16B-aligned rows (b128-safe)
#define QS 260        // f32 t-stride for Q staging (16B-aligned rows)
#define RS 68         // f32 c-stride for O reduction

// scale = ch^-0.5 (=1/8) * log2(e), folded into Q; softmax uses exp2 directly.
#define QSCALE 0.180336880972948929f

typedef __attribute__((ext_vector_type(4))) float  f32x4;
typedef __attribute__((ext_vector_type(8))) __bf16 bf16x8;
typedef __attribute__((ext_vector_type(4))) __bf16 bf16x4;
typedef __attribute__((ext_vector_type(2))) __bf16 bf16x2;
typedef __attribute__((ext_vector_type(2))) unsigned int uint2v;
typedef __attribute__((ext_vector_type(4))) unsigned int uint4v;

union SMem {
  float qstage[CH * QS];                  // 66560 B (pre-loop only)
  struct {
    __bf16 k_hi[4][KSZ];                  // 4 x 8192 B  (K^T, 4-deep ring)
    __bf16 v_s [4][CH * CS];              // 4 x 9216 B  (V, 4-deep ring)
  } loop;                                 // 69632 B
  struct {
    float o[8][WT][RS];                   // 69632 B  O^T partial exchange [wt][t][c]
    float l[2][8][4][16];                 // 4096 B   l partial [nb][wt][quad][tn]
  } red;                                  // union max = 73728 B -> 1 block/CU
};

#define MFMA(A, B, C) __builtin_amdgcn_mfma_f32_16x16x32_bf16((A), (B), (C), 0, 0, 0)

// pack two f32 -> one u32 of 2 bf16 (compiler emits v_cvt_pk_bf16_f32)
__device__ __forceinline__ unsigned pkbf2(float lo, float hi) {
  bf16x2 t = {(__bf16)lo, (__bf16)hi};
  return __builtin_bit_cast(unsigned, t);
}

// ---- K staging (early-convert: live state is bf16x8 = 4 VGPR/tile).
// Swizzle: elem ^= ((s&7)<<3). Store slot = cg^(s&7); read slot =
// (4kb+quad)^(tn&7) -> both minimum-round (verified R11).
__device__ __forceinline__ bf16x8 load_k8_cvt(const float* kp, int s0, int stid) {
  int s  = stid & 63;                     // key column
  int cg = stid >> 6;                     // channel group 0..7
  const float* kc = kp + (size_t)(8 * cg) * T_LEN + s0 + s;
  bf16x8 w;
#pragma unroll
  for (int j = 0; j < 8; ++j)
    w[j] = (__bf16)kc[(size_t)j * T_LEN]; // 64 lanes read 64 consecutive s: coalesced
  return w;
}

__device__ __forceinline__ void store_k8w(__bf16* kh, int stid, bf16x8 w) {
  int s  = stid & 63;
  int cg = stid >> 6;
  int e = (s << 6) + (cg << 3);
  *(bf16x8*)&kh[e ^ ((s & 7) << 3)] = w;
}

// ---- V staging (early-convert: live state is 2x bf16x4 = 4 VGPR/tile).
__device__ __forceinline__ void load_v_cvt(const float* vp, int s0, int ltid, bf16x4 (&vv)[2]) {
#pragma unroll
  for (int rr = 0; rr < 2; ++rr) {
    int fidx = rr * 512 + ltid;
    int c  = fidx >> 4;
    int s4 = (fidx & 15) << 2;
    f32x4 t = *(const f32x4*)(vp + (size_t)c * T_LEN + s0 + s4);
    vv[rr] = (bf16x4){(__bf16)t.x, (__bf16)t.y, (__bf16)t.z, (__bf16)t.w};
  }
}

__device__ __forceinline__ void store_vw(__bf16* vs, int ltid, const bf16x4 (&vv)[2]) {
#pragma unroll
  for (int rr = 0; rr < 2; ++rr) {
    int fidx = rr * 512 + ltid;
    int c  = fidx >> 4;
    int s4 = (fidx & 15) << 2;
    *(bf16x4*)&vs[c * CS + s4] = vv[rr];
  }
}

// NOTE (journal): arch-VGPR wall ~64 at 1024-thread blocks (acc in AGPRs;
// accum_offset 64). R8: early stores hurt (need >= 1 body of load->store
// slack). R9: cross-iter PV negative. R10: ones-MFMA l (-2us). R11: K
// swizzle; residual 3.5M SQ_LDS_BANK_CONFLICT = multi-round b128 floor.
// R12: 4-deep ring + dual early-cvt staging -> 1 barrier per 2 tiles.
__global__ __launch_bounds__(1024, 4)
void qkv_attn_mfma(const float* __restrict__ qkv, float* __restrict__ out) {
  __shared__ SMem sm;
  const int tid  = threadIdx.x;
  const int lane = tid & 63;
  const int wave = tid >> 6;     // 0..15
  const int wt   = wave & 7;     // t-eighth (32 queries each)
  const int ws   = wave >> 3;    // s-half; also staging role (0=K, 1=V)
  const int tn   = lane & 15;
  const int quad = lane >> 4;
  const int stid = tid & 511;    // local tid within staging half

  // ---- XCD-aware swizzle: 256 blocks, 8 XCDs -> 32-block chunks per XCD.
  const int d0 = blockIdx.x;
  const int w  = ((d0 & 7) << 5) | (d0 >> 3);
  const int ttile = w & 7;                 // 0..7
  const int bh    = w >> 3;                // 0..31
  const int b = bh >> 3, h = bh & 7;
  const size_t base = (size_t)b * (3 * NH * CH) * T_LEN;
  const float* qp = qkv + base + (size_t)(CH * h) * T_LEN;
  const float* kp = qkv + base + (size_t)(CH * (NH + h)) * T_LEN;
  const float* vp = qkv + base + (size_t)(CH * (2 * NH + h)) * T_LEN;
  const int t0q = ttile * TTILE;

  // ---- stage Q tile fp32 [c][t_local]  (64c x 256t = 16 f32/thread)
#pragma unroll
  for (int rr = 0; rr < 4; ++rr) {
    int fidx = rr * 1024 + tid;
    int c  = fidx >> 6;
    int t4 = (fidx & 63) << 2;
    f32x4 q4 = *(const f32x4*)(qp + (size_t)c * T_LEN + t0q + t4);
    *(f32x4*)&sm.qstage[c * QS + t4] = q4;
  }
  __syncthreads();

  // ---- build Q B-fragments: B[k=c][n=t]
  bf16x8 qh[2][2];                         // [nb][kb]
#pragma unroll
  for (int nb = 0; nb < 2; ++nb)
#pragma unroll
    for (int kb = 0; kb < 2; ++kb) {
      int tloc = wt * WT + nb * 16 + tn;
      bf16x8 H;
#pragma unroll
      for (int j = 0; j < 8; ++j) {
        float qv = sm.qstage[(kb * 32 + quad * 8 + j) * QS + tloc] * QSCALE;
        H[j] = (__bf16)qv;
      }
      qh[nb][kb] = H;
    }
  __syncthreads();   // qstage memory reused by loop arrays below

  f32x4 acc[4][2];                         // O^T partial (this ws): [mbc=c][nb=t]
  f32x4 acc_l[2];                          // l partial via ones-MFMA: [nb]
#pragma unroll
  for (int mbc = 0; mbc < 4; ++mbc)
#pragma unroll
    for (int nb = 0; nb < 2; ++nb)
      acc[mbc][nb] = (f32x4){0.f, 0.f, 0.f, 0.f};
  acc_l[0] = (f32x4){0.f, 0.f, 0.f, 0.f};
  acc_l[1] = (f32x4){0.f, 0.f, 0.f, 0.f};

  // ones A-fragment: l[t] = sum_s 1 * P[s][t] (every output row = full l)
  bf16x8 av_one;
#pragma unroll
  for (int j = 0; j < 8; ++j) av_one[j] = (__bf16)1.0f;

  // ---- per-tile compute body (R5/R10 shape, buffer index bi)
  auto body = [&](int bi) {
    const __bf16* kh = sm.loop.k_hi[bi];
    const __bf16* vs = sm.loop.v_s[bi];
    const int swz = (tn & 7) << 3;
    bf16x8 ah[2][2];
#pragma unroll
    for (int mb = 0; mb < 2; ++mb) {
      const int srow = 32 * ws + 16 * mb + tn;          // srow&7 == tn&7
#pragma unroll
      for (int kb = 0; kb < 2; ++kb) {
        int e = (srow << 6) + 32 * kb + 8 * quad;
        ah[mb][kb] = *(const bf16x8*)&kh[e ^ swz];
      }
    }
    f32x4 d[2][2];
#pragma unroll
    for (int mb = 0; mb < 2; ++mb)
#pragma unroll
      for (int nb = 0; nb < 2; ++nb) {
        f32x4 t = (f32x4){0.f, 0.f, 0.f, 0.f};
        t = MFMA(ah[mb][0], qh[nb][0], t);
        t = MFMA(ah[mb][1], qh[nb][1], t);
        d[mb][nb] = t;
      }

    bf16x8 av[4];
#pragma unroll
    for (int mbc = 0; mbc < 4; ++mbc)
      av[mbc] = *(const bf16x8*)&vs[(16 * mbc + tn) * CS + 32 * ws + quad * 8];

    // p = exp2(s'); in-register redistribution to PV B-fragment (verified).
    bf16x8 bp[2];
#pragma unroll
    for (int nb = 0; nb < 2; ++nb) {
#pragma unroll
      for (int mb = 0; mb < 2; ++mb)
#pragma unroll
        for (int r = 0; r < 4; ++r)
          d[mb][nb][r] = __builtin_amdgcn_exp2f(d[mb][nb][r]);
      unsigned u00 = pkbf2(d[0][nb][0], d[0][nb][1]);
      unsigned u01 = pkbf2(d[0][nb][2], d[0][nb][3]);
      unsigned u10 = pkbf2(d[1][nb][0], d[1][nb][1]);
      unsigned u11 = pkbf2(d[1][nb][2], d[1][nb][3]);
      uint2v s0 = __builtin_amdgcn_permlane32_swap(u00, u10, false, false);
      uint2v r0 = __builtin_amdgcn_permlane16_swap(s0.x, s0.y, false, false);
      uint2v s1 = __builtin_amdgcn_permlane32_swap(u01, u11, false, false);
      uint2v r1 = __builtin_amdgcn_permlane16_swap(s1.x, s1.y, false, false);
      uint4v wv = {r0.x, r1.x, r0.y, r1.y};   // w0,w1,w2,w3 -> j=0..7
      bp[nb] = __builtin_bit_cast(bf16x8, wv);
    }

#pragma unroll
    for (int mbc = 0; mbc < 4; ++mbc)
#pragma unroll
      for (int nb = 0; nb < 2; ++nb)
        acc[mbc][nb] = MFMA(av[mbc], bp[nb], acc[mbc][nb]);
#pragma unroll
    for (int nb = 0; nb < 2; ++nb)
      acc_l[nb] = MFMA(av_one, bp[nb], acc_l[nb]);
  };

  // ---- prologue: stage tiles 0 and 1
  bf16x8 kbA, kbB;
  bf16x4 vvA[2], vvB[2];
  if (ws == 0) {
    kbA = load_k8_cvt(kp, 0,     stid);
    kbB = load_k8_cvt(kp, STILE, stid);
    store_k8w(sm.loop.k_hi[0], stid, kbA);
    store_k8w(sm.loop.k_hi[1], stid, kbB);
  } else {
    load_v_cvt(vp, 0,     stid, vvA);
    load_v_cvt(vp, STILE, stid, vvB);
    store_vw(sm.loop.v_s[0], stid, vvA);
    store_vw(sm.loop.v_s[1], stid, vvB);
  }
  __syncthreads();

  // ---- main loop: one barrier per PAIR of tiles (16 barriers, not 32).
  // Pair p reads buffers {2p&3,(2p+1)&3}, stages {(2p+2)&3,(2p+3)&3} —
  // disjoint mod 4 -> no intra-pair race; pair-end barrier publishes both.
  for (int p = 0; p < NIT / 2; ++p) {
    const int t0 = 2 * p;
    const bool more = (p + 1 < NIT / 2);

    if (more) {
      if (ws == 0) {
        kbA = load_k8_cvt(kp, (t0 + 2) * STILE, stid);
        kbB = load_k8_cvt(kp, (t0 + 3) * STILE, stid);
      } else {
        load_v_cvt(vp, (t0 + 2) * STILE, stid, vvA);
        load_v_cvt(vp, (t0 + 3) * STILE, stid, vvB);
      }
    }

    body(t0 & 3);

    if (more) {                 // store tile t0+2 (one body of load slack)
      if (ws == 0) store_k8w(sm.loop.k_hi[(t0 + 2) & 3], stid, kbA);
      else         store_vw (sm.loop.v_s [(t0 + 2) & 3], stid, vvA);
    }

    body((t0 + 1) & 3);

    if (more) {                 // store tile t0+3 (two bodies of slack)
      if (ws == 0) store_k8w(sm.loop.k_hi[(t0 + 3) & 3], stid, kbB);
      else         store_vw (sm.loop.v_s [(t0 + 3) & 3], stid, vvB);
    }
    __syncthreads();
  }

  // l_part[nb]: every row of the ones-MFMA tile equals the full column sum
  // over this ws's keys, so any one register slot is the complete partial.
  float l_part[2] = {acc_l[0][0], acc_l[1][0]};

  // ---- cross-ws reduction: ws=1 publishes partials, ws=0 combines + stores
  if (ws == 1) {
#pragma unroll
    for (int nb = 0; nb < 2; ++nb) {
      sm.red.l[nb][wt][quad][tn] = l_part[nb];
#pragma unroll
      for (int mbc = 0; mbc < 4; ++mbc)
        *(f32x4*)&sm.red.o[wt][nb * 16 + tn][16 * mbc + quad * 4] = acc[mbc][nb];
    }
  }
  __syncthreads();
  if (ws == 0) {
    float* op = out + (size_t)bh * CH * T_LEN;
#pragma unroll
    for (int nb = 0; nb < 2; ++nb) {
      // full-tile sums already include all 4 quads -> NO shfl reduction here
      float l = l_part[nb] + sm.red.l[nb][wt][quad][tn];
      float inv_l = 1.0f / l;
      int t = t0q + wt * WT + nb * 16 + tn;
#pragma unroll
      for (int mbc = 0; mbc < 4; ++mbc) {
        f32x4 o = acc[mbc][nb] + *(const f32x4*)&sm.red.o[wt][nb * 16 + tn][16 * mbc + quad * 4];
        o = o * inv_l;
        int c = 16 * mbc + quad * 4;
        op[(size_t)(c + 0) * T_LEN + t] = o.x;
        op[(size_t)(c + 1) * T_LEN + t] = o.y;
        op[(size_t)(c + 2) * T_LEN + t] = o.z;
        op[(size_t)(c + 3) * T_LEN + t] = o.w;
      }
    }
  }
}

extern "C" void kernel_launch(void* const* d_in, const int* in_sizes, int n_in,
                              void* d_out, int out_size, void* d_ws, size_t ws_size,
                              hipStream_t stream) {
  const float* qkv = (const float*)d_in[0];
  float* out = (float*)d_out;
  dim3 grid(256);   // 256 blocks of 1024 threads (XCD-swizzled in-kernel)
  qkv_attn_mfma<<<grid, 1024, 0, stream>>>(qkv, out);
}

// Round 13
// 118.828 us; speedup vs baseline: 1.0668x; 1.0668x over previous
//
#include <hip/hip_runtime.h>

#define T_LEN 2048
#define CH 64
#define NH 8
#define STILE 64      // keys per block-iteration (split 2 ways across ws)
#define TTILE 256     // queries per block (split 8 ways across wt)
#define WT 32         // queries per wave
#define NIT (T_LEN / STILE)   // 32
#define KSZ (STILE * CH)      // k_hi elems per buffer (64x64, no pad, XOR-swizzled)
#define CS 72         // v_s row stride (bf16), 16B-aligned rows (b128-safe)
#define QS 260        // f32 t-stride for Q staging (16B-aligned rows)
#define RS 68         // f32 c-stride for O reduction

// scale = ch^-0.5 (=1/8) * log2(e), folded into Q; softmax uses exp2 directly.
#define QSCALE 0.180336880972948929f

typedef __attribute__((ext_vector_type(4))) float  f32x4;
typedef __attribute__((ext_vector_type(8))) __bf16 bf16x8;
typedef __attribute__((ext_vector_type(4))) __bf16 bf16x4;
typedef __attribute__((ext_vector_type(2))) __bf16 bf16x2;
typedef __attribute__((ext_vector_type(2))) unsigned int uint2v;
typedef __attribute__((ext_vector_type(4))) unsigned int uint4v;

union SMem {
  float qstage[CH * QS];                  // 66560 B (pre-loop only)
  struct {
    __bf16 k_hi[2][KSZ];                  // 2 x 8192 B  (K^T, XOR-swizzled rows)
    __bf16 v_s [2][CH * CS];              // 2 x 9216 B  (V, double-buffered)
  } loop;                                 // 34816 B
  struct {
    float o[8][WT][RS];                   // 69632 B  O^T partial exchange [wt][t][c]
    float l[2][8][4][16];                 // 4096 B   l partial [nb][wt][quad][tn]
  } red;                                  // union max = 73728 B -> 1 block/CU
};

#define MFMA(A, B, C) __builtin_amdgcn_mfma_f32_16x16x32_bf16((A), (B), (C), 0, 0, 0)

// pack two f32 -> one u32 of 2 bf16 (compiler emits v_cvt_pk_bf16_f32)
__device__ __forceinline__ unsigned pkbf2(float lo, float hi) {
  bf16x2 t = {(__bf16)lo, (__bf16)hi};
  return __builtin_bit_cast(unsigned, t);
}

// ---- K staging: row s (key), cols 8cg..8cg+7 (channels), XOR-swizzled.
// Swizzle: elem ^= ((s&7)<<3). Store slot = cg^(s&7); read slot =
// (4kb+quad)^(tn&7) -> both minimum-round conflict-free (verified R11).
__device__ __forceinline__ void load_k8(const float* kp, int s0, int stid, float (&kr)[8]) {
  int s  = stid & 63;                     // key column
  int cg = stid >> 6;                     // channel group 0..7
  const float* kc = kp + (size_t)(8 * cg) * T_LEN + s0 + s;
#pragma unroll
  for (int j = 0; j < 8; ++j)
    kr[j] = kc[(size_t)j * T_LEN];        // 64 lanes read 64 consecutive s: coalesced
}

__device__ __forceinline__ void store_k8(__bf16* kh, int stid, const float (&kr)[8]) {
  int s  = stid & 63;
  int cg = stid >> 6;
  bf16x8 w;
#pragma unroll
  for (int j = 0; j < 8; ++j) w[j] = (__bf16)kr[j];
  int e = (s << 6) + (cg << 3);
  *(bf16x8*)&kh[e ^ ((s & 7) << 3)] = w;
}

__device__ __forceinline__ void load_v(const float* vp, int s0, int ltid, f32x4 (&vreg)[2]) {
#pragma unroll
  for (int rr = 0; rr < 2; ++rr) {
    int fidx = rr * 512 + ltid;
    int c  = fidx >> 4;
    int s4 = (fidx & 15) << 2;
    vreg[rr] = *(const f32x4*)(vp + (size_t)c * T_LEN + s0 + s4);
  }
}

__device__ __forceinline__ void store_v(__bf16* vs, int ltid, const f32x4 (&vreg)[2]) {
#pragma unroll
  for (int rr = 0; rr < 2; ++rr) {
    int fidx = rr * 512 + ltid;
    int c  = fidx >> 4;
    int s4 = (fidx & 15) << 2;
    bf16x4 vv = {(__bf16)vreg[rr].x, (__bf16)vreg[rr].y,
                 (__bf16)vreg[rr].z, (__bf16)vreg[rr].w};
    *(bf16x4*)&vs[c * CS + s4] = vv;
  }
}

// NOTE (journal): arch-VGPR wall ~64 at 1024-thread blocks (acc in AGPRs).
// R8/R12: staging stores need a FULL iteration of load slack — barrier-
// reduction line closed (R6/R7 spill, R12 -13%). R9: cross-iter PV negative.
// R10: ones-MFMA l (-2us). R11: conflict-free swizzled K (best, ~54us);
// residual 3.5M SQ_LDS_BANK_CONFLICT = multi-round b128 floor.
// R13: R11 + isolated s_setprio around MFMA clusters (T5 A/B).
__global__ __launch_bounds__(1024, 4)
void qkv_attn_mfma(const float* __restrict__ qkv, float* __restrict__ out) {
  __shared__ SMem sm;
  const int tid  = threadIdx.x;
  const int lane = tid & 63;
  const int wave = tid >> 6;     // 0..15
  const int wt   = wave & 7;     // t-eighth (32 queries each)
  const int ws   = wave >> 3;    // s-half; also staging role (0=K, 1=V)
  const int tn   = lane & 15;
  const int quad = lane >> 4;
  const int stid = tid & 511;    // local tid within staging half

  // ---- XCD-aware swizzle: 256 blocks, 8 XCDs -> 32-block chunks per XCD.
  const int d0 = blockIdx.x;
  const int w  = ((d0 & 7) << 5) | (d0 >> 3);
  const int ttile = w & 7;                 // 0..7
  const int bh    = w >> 3;                // 0..31
  const int b = bh >> 3, h = bh & 7;
  const size_t base = (size_t)b * (3 * NH * CH) * T_LEN;
  const float* qp = qkv + base + (size_t)(CH * h) * T_LEN;
  const float* kp = qkv + base + (size_t)(CH * (NH + h)) * T_LEN;
  const float* vp = qkv + base + (size_t)(CH * (2 * NH + h)) * T_LEN;
  const int t0 = ttile * TTILE;

  // ---- stage Q tile fp32 [c][t_local]  (64c x 256t = 16 f32/thread)
#pragma unroll
  for (int rr = 0; rr < 4; ++rr) {
    int fidx = rr * 1024 + tid;
    int c  = fidx >> 6;
    int t4 = (fidx & 63) << 2;
    f32x4 q4 = *(const f32x4*)(qp + (size_t)c * T_LEN + t0 + t4);
    *(f32x4*)&sm.qstage[c * QS + t4] = q4;
  }
  __syncthreads();

  // ---- build Q B-fragments: B[k=c][n=t]
  bf16x8 qh[2][2];                         // [nb][kb]
#pragma unroll
  for (int nb = 0; nb < 2; ++nb)
#pragma unroll
    for (int kb = 0; kb < 2; ++kb) {
      int tloc = wt * WT + nb * 16 + tn;
      bf16x8 H;
#pragma unroll
      for (int j = 0; j < 8; ++j) {
        float qv = sm.qstage[(kb * 32 + quad * 8 + j) * QS + tloc] * QSCALE;
        H[j] = (__bf16)qv;
      }
      qh[nb][kb] = H;
    }
  __syncthreads();   // qstage memory reused by loop arrays below

  f32x4 acc[4][2];                         // O^T partial (this ws): [mbc=c][nb=t]
  f32x4 acc_l[2];                          // l partial via ones-MFMA: [nb]
#pragma unroll
  for (int mbc = 0; mbc < 4; ++mbc)
#pragma unroll
    for (int nb = 0; nb < 2; ++nb)
      acc[mbc][nb] = (f32x4){0.f, 0.f, 0.f, 0.f};
  acc_l[0] = (f32x4){0.f, 0.f, 0.f, 0.f};
  acc_l[1] = (f32x4){0.f, 0.f, 0.f, 0.f};

  // ones A-fragment: l[t] = sum_s 1 * P[s][t] (every output row = full l)
  bf16x8 av_one;
#pragma unroll
  for (int j = 0; j < 8; ++j) av_one[j] = (__bf16)1.0f;

  // ---- prologue: stage tile 0 (waves 0-7 stage K, waves 8-15 stage V)
  float  kreg[8];
  f32x4  vreg[2];
  if (ws == 0) { load_k8(kp, 0, stid, kreg); store_k8(sm.loop.k_hi[0], stid, kreg); }
  else         { load_v (vp, 0, stid, vreg); store_v (sm.loop.v_s[0], stid, vreg); }
  __syncthreads();

  for (int it = 0; it < NIT; ++it) {
    const int cur = it & 1;
    const bool more = (it + 1 < NIT);

    // ---- global prefetch of tile it+1 (latency hidden under QK/softmax/PV)
    if (more) {
      if (ws == 0) load_k8(kp, (it + 1) * STILE, stid, kreg);
      else         load_v (vp, (it + 1) * STILE, stid, vreg);
    }

    // ---- QK(it): wave's s-half (2 mb rows), its t-eighth.
    // Single b128 per (mb,kb), conflict-free via the K swizzle.
    const __bf16* kh = sm.loop.k_hi[cur];
    const int swz = (tn & 7) << 3;
    bf16x8 ah[2][2];
#pragma unroll
    for (int mb = 0; mb < 2; ++mb) {
      const int srow = 32 * ws + 16 * mb + tn;          // srow&7 == tn&7
#pragma unroll
      for (int kb = 0; kb < 2; ++kb) {
        int e = (srow << 6) + 32 * kb + 8 * quad;
        ah[mb][kb] = *(const bf16x8*)&kh[e ^ swz];
      }
    }
    __builtin_amdgcn_s_setprio(1);
    f32x4 d[2][2];
#pragma unroll
    for (int mb = 0; mb < 2; ++mb)
#pragma unroll
      for (int nb = 0; nb < 2; ++nb) {
        f32x4 t = (f32x4){0.f, 0.f, 0.f, 0.f};
        t = MFMA(ah[mb][0], qh[nb][0], t);
        t = MFMA(ah[mb][1], qh[nb][1], t);
        d[mb][nb] = t;
      }
    __builtin_amdgcn_s_setprio(0);

    // ---- issue V fragment reads early (latency hidden under softmax VALU)
    const __bf16* vs = sm.loop.v_s[cur];
    bf16x8 av[4];
#pragma unroll
    for (int mbc = 0; mbc < 4; ++mbc)
      av[mbc] = *(const bf16x8*)&vs[(16 * mbc + tn) * CS + 32 * ws + quad * 8];

    // ---- p = exp2(s'), then in-register redistribution to PV B-fragment.
    // QK C/D layout: lane(q,tn) holds P[s=16mb+4q+r][t=tn]. PV B-frag needs
    // P[s=8q+j][t=tn]. (w0,w2)=SW16(SW32(u00,u10)); (w1,w3)=SW16(SW32(u01,u11)).
    bf16x8 bp[2];
#pragma unroll
    for (int nb = 0; nb < 2; ++nb) {
#pragma unroll
      for (int mb = 0; mb < 2; ++mb)
#pragma unroll
        for (int r = 0; r < 4; ++r)
          d[mb][nb][r] = __builtin_amdgcn_exp2f(d[mb][nb][r]);
      unsigned u00 = pkbf2(d[0][nb][0], d[0][nb][1]);
      unsigned u01 = pkbf2(d[0][nb][2], d[0][nb][3]);
      unsigned u10 = pkbf2(d[1][nb][0], d[1][nb][1]);
      unsigned u11 = pkbf2(d[1][nb][2], d[1][nb][3]);
      uint2v s0 = __builtin_amdgcn_permlane32_swap(u00, u10, false, false);
      uint2v r0 = __builtin_amdgcn_permlane16_swap(s0.x, s0.y, false, false);
      uint2v s1 = __builtin_amdgcn_permlane32_swap(u01, u11, false, false);
      uint2v r1 = __builtin_amdgcn_permlane16_swap(s1.x, s1.y, false, false);
      uint4v wv = {r0.x, r1.x, r0.y, r1.y};   // w0,w1,w2,w3 -> j=0..7
      bp[nb] = __builtin_bit_cast(bf16x8, wv);
    }

    // ---- PV(it) + l via ones-row MFMA (full 32-key column sums)
    __builtin_amdgcn_s_setprio(1);
#pragma unroll
    for (int mbc = 0; mbc < 4; ++mbc)
#pragma unroll
      for (int nb = 0; nb < 2; ++nb)
        acc[mbc][nb] = MFMA(av[mbc], bp[nb], acc[mbc][nb]);
#pragma unroll
    for (int nb = 0; nb < 2; ++nb)
      acc_l[nb] = MFMA(av_one, bp[nb], acc_l[nb]);
    __builtin_amdgcn_s_setprio(0);

    // ---- stage tile it+1 LATE (prefetch had the whole iteration in flight)
    if (more) {
      if (ws == 0) store_k8(sm.loop.k_hi[cur ^ 1], stid, kreg);
      else         store_v (sm.loop.v_s [cur ^ 1], stid, vreg);
    }
    __syncthreads();
  }

  // l_part[nb]: every row of the ones-MFMA tile equals the full column sum
  // over this ws's keys, so any one register slot is the complete partial.
  float l_part[2] = {acc_l[0][0], acc_l[1][0]};

  // ---- cross-ws reduction: ws=1 publishes partials, ws=0 combines + stores
  if (ws == 1) {
#pragma unroll
    for (int nb = 0; nb < 2; ++nb) {
      sm.red.l[nb][wt][quad][tn] = l_part[nb];
#pragma unroll
      for (int mbc = 0; mbc < 4; ++mbc)
        *(f32x4*)&sm.red.o[wt][nb * 16 + tn][16 * mbc + quad * 4] = acc[mbc][nb];
    }
  }
  __syncthreads();
  if (ws == 0) {
    float* op = out + (size_t)bh * CH * T_LEN;
#pragma unroll
    for (int nb = 0; nb < 2; ++nb) {
      // full-tile sums already include all 4 quads -> NO shfl reduction here
      float l = l_part[nb] + sm.red.l[nb][wt][quad][tn];
      float inv_l = 1.0f / l;
      int t = t0 + wt * WT + nb * 16 + tn;
#pragma unroll
      for (int mbc = 0; mbc < 4; ++mbc) {
        f32x4 o = acc[mbc][nb] + *(const f32x4*)&sm.red.o[wt][nb * 16 + tn][16 * mbc + quad * 4];
        o = o * inv_l;
        int c = 16 * mbc + quad * 4;
        op[(size_t)(c + 0) * T_LEN + t] = o.x;
        op[(size_t)(c + 1) * T_LEN + t] = o.y;
        op[(size_t)(c + 2) * T_LEN + t] = o.z;
        op[(size_t)(c + 3) * T_LEN + t] = o.w;
      }
    }
  }
}

extern "C" void kernel_launch(void* const* d_in, const int* in_sizes, int n_in,
                              void* d_out, int out_size, void* d_ws, size_t ws_size,
                              hipStream_t stream) {
  const float* qkv = (const float*)d_in[0];
  float* out = (float*)d_out;
  dim3 grid(256);   // 256 blocks of 1024 threads (XCD-swizzled in-kernel)
  qkv_attn_mfma<<<grid, 1024, 0, stream>>>(qkv, out);
}

// Round 14
// 118.525 us; speedup vs baseline: 1.0695x; 1.0026x over previous
//
#include <hip/hip_runtime.h>

#define T_LEN 2048
#define CH 64
#define NH 8
#define STILE 64      // keys per block-iteration (split 2 ways across ws)
#define TTILE 256     // queries per block (split 8 ways across wt)
#define WT 32         // queries per wave
#define NIT (T_LEN / STILE)   // 32
#define KSZ (STILE * CH)      // k_hi elems per buffer (64x64, no pad, XOR-swizzled)
#define CS 72         // v_s row stride (bf16), 16B-aligned rows (b128-safe)
#define QS 260        // f32 t-stride for Q staging (16B-aligned rows)
#define RS 68         // f32 c-stride for O reduction

// scale = ch^-0.5 (=1/8) * log2(e), folded into Q; softmax uses exp2 directly.
#define QSCALE 0.180336880972948929f

typedef __attribute__((ext_vector_type(4))) float  f32x4;
typedef __attribute__((ext_vector_type(8))) __bf16 bf16x8;
typedef __attribute__((ext_vector_type(4))) __bf16 bf16x4;
typedef __attribute__((ext_vector_type(2))) __bf16 bf16x2;
typedef __attribute__((ext_vector_type(2))) unsigned int uint2v;
typedef __attribute__((ext_vector_type(4))) unsigned int uint4v;

union SMem {
  float qstage[CH * QS];                  // 66560 B (pre-loop only)
  struct {
    __bf16 k_hi[2][KSZ];                  // 2 x 8192 B  (K^T, XOR-swizzled rows)
    __bf16 v_s [2][CH * CS];              // 2 x 9216 B  (V, double-buffered)
  } loop;                                 // 34816 B
  struct {
    float o[8][WT][RS];                   // 69632 B  O^T partial exchange [wt][t][c]
    float l[2][8][4][16];                 // 4096 B   l partial [nb][wt][quad][tn]
  } red;                                  // union max = 73728 B -> 1 block/CU
};

#define MFMA(A, B, C) __builtin_amdgcn_mfma_f32_16x16x32_bf16((A), (B), (C), 0, 0, 0)

// pack two f32 -> one u32 of 2 bf16 (v_cvt_pk_bf16_f32)
__device__ __forceinline__ unsigned pkbf2(float lo, float hi) {
  bf16x2 t = {(__bf16)lo, (__bf16)hi};
  return __builtin_bit_cast(unsigned, t);
}

// ---- K staging: row s (key), cols 8cg..8cg+7 (channels), XOR-swizzled.
// Swizzle: elem ^= ((s&7)<<3). Store slot = cg^(s&7); read slot =
// (4kb+quad)^(tn&7) -> both minimum-round conflict-free (verified R11).
__device__ __forceinline__ void load_k8(const float* kp, int s0, int stid, float (&kr)[8]) {
  int s  = stid & 63;                     // key column
  int cg = stid >> 6;                     // channel group 0..7
  const float* kc = kp + (size_t)(8 * cg) * T_LEN + s0 + s;
#pragma unroll
  for (int j = 0; j < 8; ++j)
    kr[j] = kc[(size_t)j * T_LEN];        // 64 lanes read 64 consecutive s: coalesced
}

__device__ __forceinline__ void store_k8(__bf16* kh, int stid, const float (&kr)[8]) {
  int s  = stid & 63;
  int cg = stid >> 6;
  uint4v wv = {pkbf2(kr[0], kr[1]), pkbf2(kr[2], kr[3]),
               pkbf2(kr[4], kr[5]), pkbf2(kr[6], kr[7])};   // 4 packed cvts
  bf16x8 w = __builtin_bit_cast(bf16x8, wv);
  int e = (s << 6) + (cg << 3);
  *(bf16x8*)&kh[e ^ ((s & 7) << 3)] = w;
}

// ---- V staging: one thread = one 8-key run of one channel row.
// c = ltid>>3 (0..63), s8 = (ltid&7)*8. Global: 2x f32x4 = 32B contiguous
// per thread; 8 threads/row cover 256B contiguous (coalesced). LDS: single
// b128 write at elem c*CS + s8; 16B-slot = (9c + (lane&7)) & 7 = (c+(lane&7))&7
// -> 8 distinct slots per 8-lane group = minimum-round conflict-free.
__device__ __forceinline__ void load_v(const float* vp, int s0, int ltid, f32x4 (&vreg)[2]) {
  int c  = ltid >> 3;
  int s8 = (ltid & 7) << 3;
  const float* vc = vp + (size_t)c * T_LEN + s0 + s8;
  vreg[0] = *(const f32x4*)(vc);
  vreg[1] = *(const f32x4*)(vc + 4);
}

__device__ __forceinline__ void store_v(__bf16* vs, int ltid, const f32x4 (&vreg)[2]) {
  int c  = ltid >> 3;
  int s8 = (ltid & 7) << 3;
  uint4v wv = {pkbf2(vreg[0].x, vreg[0].y), pkbf2(vreg[0].z, vreg[0].w),
               pkbf2(vreg[1].x, vreg[1].y), pkbf2(vreg[1].z, vreg[1].w)};
  *(bf16x8*)&vs[c * CS + s8] = __builtin_bit_cast(bf16x8, wv);
}

// NOTE (journal): arch-VGPR wall ~64 at 1024-thread blocks (acc in AGPRs).
// R8/R12: staging loads must not be consumed early (cvt at STORE, not load);
// barrier-reduction closed (R6/R7 spill, R12 early-cvt confound). R9: cross-
// iter PV negative. R10: ones-MFMA l (-2us). R11: conflict-free swizzled K
// (best ~54us); residual 3.5M SQ_LDS_BANK_CONFLICT = multi-round b128 floor.
// R13: setprio neutral (kept). R14: packed cvts + b128 V-store (VALU cut).
__global__ __launch_bounds__(1024, 4)
void qkv_attn_mfma(const float* __restrict__ qkv, float* __restrict__ out) {
  __shared__ SMem sm;
  const int tid  = threadIdx.x;
  const int lane = tid & 63;
  const int wave = tid >> 6;     // 0..15
  const int wt   = wave & 7;     // t-eighth (32 queries each)
  const int ws   = wave >> 3;    // s-half; also staging role (0=K, 1=V)
  const int tn   = lane & 15;
  const int quad = lane >> 4;
  const int stid = tid & 511;    // local tid within staging half

  // ---- XCD-aware swizzle: 256 blocks, 8 XCDs -> 32-block chunks per XCD.
  const int d0 = blockIdx.x;
  const int w  = ((d0 & 7) << 5) | (d0 >> 3);
  const int ttile = w & 7;                 // 0..7
  const int bh    = w >> 3;                // 0..31
  const int b = bh >> 3, h = bh & 7;
  const size_t base = (size_t)b * (3 * NH * CH) * T_LEN;
  const float* qp = qkv + base + (size_t)(CH * h) * T_LEN;
  const float* kp = qkv + base + (size_t)(CH * (NH + h)) * T_LEN;
  const float* vp = qkv + base + (size_t)(CH * (2 * NH + h)) * T_LEN;
  const int t0 = ttile * TTILE;

  // ---- stage Q tile fp32 [c][t_local]  (64c x 256t = 16 f32/thread)
#pragma unroll
  for (int rr = 0; rr < 4; ++rr) {
    int fidx = rr * 1024 + tid;
    int c  = fidx >> 6;
    int t4 = (fidx & 63) << 2;
    f32x4 q4 = *(const f32x4*)(qp + (size_t)c * T_LEN + t0 + t4);
    *(f32x4*)&sm.qstage[c * QS + t4] = q4;
  }
  __syncthreads();

  // ---- build Q B-fragments: B[k=c][n=t]
  bf16x8 qh[2][2];                         // [nb][kb]
#pragma unroll
  for (int nb = 0; nb < 2; ++nb)
#pragma unroll
    for (int kb = 0; kb < 2; ++kb) {
      int tloc = wt * WT + nb * 16 + tn;
      bf16x8 H;
#pragma unroll
      for (int j = 0; j < 8; ++j) {
        float qv = sm.qstage[(kb * 32 + quad * 8 + j) * QS + tloc] * QSCALE;
        H[j] = (__bf16)qv;
      }
      qh[nb][kb] = H;
    }
  __syncthreads();   // qstage memory reused by loop arrays below

  f32x4 acc[4][2];                         // O^T partial (this ws): [mbc=c][nb=t]
  f32x4 acc_l[2];                          // l partial via ones-MFMA: [nb]
#pragma unroll
  for (int mbc = 0; mbc < 4; ++mbc)
#pragma unroll
    for (int nb = 0; nb < 2; ++nb)
      acc[mbc][nb] = (f32x4){0.f, 0.f, 0.f, 0.f};
  acc_l[0] = (f32x4){0.f, 0.f, 0.f, 0.f};
  acc_l[1] = (f32x4){0.f, 0.f, 0.f, 0.f};

  // ones A-fragment: l[t] = sum_s 1 * P[s][t] (every output row = full l)
  bf16x8 av_one;
#pragma unroll
  for (int j = 0; j < 8; ++j) av_one[j] = (__bf16)1.0f;

  // ---- prologue: stage tile 0 (waves 0-7 stage K, waves 8-15 stage V)
  float  kreg[8];
  f32x4  vreg[2];
  if (ws == 0) { load_k8(kp, 0, stid, kreg); store_k8(sm.loop.k_hi[0], stid, kreg); }
  else         { load_v (vp, 0, stid, vreg); store_v (sm.loop.v_s[0], stid, vreg); }
  __syncthreads();

  for (int it = 0; it < NIT; ++it) {
    const int cur = it & 1;
    const bool more = (it + 1 < NIT);

    // ---- global prefetch of tile it+1 (latency hidden under QK/softmax/PV)
    if (more) {
      if (ws == 0) load_k8(kp, (it + 1) * STILE, stid, kreg);
      else         load_v (vp, (it + 1) * STILE, stid, vreg);
    }

    // ---- QK(it): wave's s-half (2 mb rows), its t-eighth.
    // Single b128 per (mb,kb), conflict-free via the K swizzle.
    const __bf16* kh = sm.loop.k_hi[cur];
    const int swz = (tn & 7) << 3;
    bf16x8 ah[2][2];
#pragma unroll
    for (int mb = 0; mb < 2; ++mb) {
      const int srow = 32 * ws + 16 * mb + tn;          // srow&7 == tn&7
#pragma unroll
      for (int kb = 0; kb < 2; ++kb) {
        int e = (srow << 6) + 32 * kb + 8 * quad;
        ah[mb][kb] = *(const bf16x8*)&kh[e ^ swz];
      }
    }
    __builtin_amdgcn_s_setprio(1);
    f32x4 d[2][2];
#pragma unroll
    for (int mb = 0; mb < 2; ++mb)
#pragma unroll
      for (int nb = 0; nb < 2; ++nb) {
        f32x4 t = (f32x4){0.f, 0.f, 0.f, 0.f};
        t = MFMA(ah[mb][0], qh[nb][0], t);
        t = MFMA(ah[mb][1], qh[nb][1], t);
        d[mb][nb] = t;
      }
    __builtin_amdgcn_s_setprio(0);

    // ---- issue V fragment reads early (latency hidden under softmax VALU)
    const __bf16* vs = sm.loop.v_s[cur];
    bf16x8 av[4];
#pragma unroll
    for (int mbc = 0; mbc < 4; ++mbc)
      av[mbc] = *(const bf16x8*)&vs[(16 * mbc + tn) * CS + 32 * ws + quad * 8];

    // ---- p = exp2(s'), then in-register redistribution to PV B-fragment.
    // QK C/D layout: lane(q,tn) holds P[s=16mb+4q+r][t=tn]. PV B-frag needs
    // P[s=8q+j][t=tn]. (w0,w2)=SW16(SW32(u00,u10)); (w1,w3)=SW16(SW32(u01,u11)).
    bf16x8 bp[2];
#pragma unroll
    for (int nb = 0; nb < 2; ++nb) {
#pragma unroll
      for (int mb = 0; mb < 2; ++mb)
#pragma unroll
        for (int r = 0; r < 4; ++r)
          d[mb][nb][r] = __builtin_amdgcn_exp2f(d[mb][nb][r]);
      unsigned u00 = pkbf2(d[0][nb][0], d[0][nb][1]);
      unsigned u01 = pkbf2(d[0][nb][2], d[0][nb][3]);
      unsigned u10 = pkbf2(d[1][nb][0], d[1][nb][1]);
      unsigned u11 = pkbf2(d[1][nb][2], d[1][nb][3]);
      uint2v s0 = __builtin_amdgcn_permlane32_swap(u00, u10, false, false);
      uint2v r0 = __builtin_amdgcn_permlane16_swap(s0.x, s0.y, false, false);
      uint2v s1 = __builtin_amdgcn_permlane32_swap(u01, u11, false, false);
      uint2v r1 = __builtin_amdgcn_permlane16_swap(s1.x, s1.y, false, false);
      uint4v wv = {r0.x, r1.x, r0.y, r1.y};   // w0,w1,w2,w3 -> j=0..7
      bp[nb] = __builtin_bit_cast(bf16x8, wv);
    }

    // ---- PV(it) + l via ones-row MFMA (full 32-key column sums)
    __builtin_amdgcn_s_setprio(1);
#pragma unroll
    for (int mbc = 0; mbc < 4; ++mbc)
#pragma unroll
      for (int nb = 0; nb < 2; ++nb)
        acc[mbc][nb] = MFMA(av[mbc], bp[nb], acc[mbc][nb]);
#pragma unroll
    for (int nb = 0; nb < 2; ++nb)
      acc_l[nb] = MFMA(av_one, bp[nb], acc_l[nb]);
    __builtin_amdgcn_s_setprio(0);

    // ---- stage tile it+1 LATE (prefetch had the whole iteration in flight)
    if (more) {
      if (ws == 0) store_k8(sm.loop.k_hi[cur ^ 1], stid, kreg);
      else         store_v (sm.loop.v_s [cur ^ 1], stid, vreg);
    }
    __syncthreads();
  }

  // l_part[nb]: every row of the ones-MFMA tile equals the full column sum
  // over this ws's keys, so any one register slot is the complete partial.
  float l_part[2] = {acc_l[0][0], acc_l[1][0]};

  // ---- cross-ws reduction: ws=1 publishes partials, ws=0 combines + stores
  if (ws == 1) {
#pragma unroll
    for (int nb = 0; nb < 2; ++nb) {
      sm.red.l[nb][wt][quad][tn] = l_part[nb];
#pragma unroll
      for (int mbc = 0; mbc < 4; ++mbc)
        *(f32x4*)&sm.red.o[wt][nb * 16 + tn][16 * mbc + quad * 4] = acc[mbc][nb];
    }
  }
  __syncthreads();
  if (ws == 0) {
    float* op = out + (size_t)bh * CH * T_LEN;
#pragma unroll
    for (int nb = 0; nb < 2; ++nb) {
      // full-tile sums already include all 4 quads -> NO shfl reduction here
      float l = l_part[nb] + sm.red.l[nb][wt][quad][tn];
      float inv_l = 1.0f / l;
      int t = t0 + wt * WT + nb * 16 + tn;
#pragma unroll
      for (int mbc = 0; mbc < 4; ++mbc) {
        f32x4 o = acc[mbc][nb] + *(const f32x4*)&sm.red.o[wt][nb * 16 + tn][16 * mbc + quad * 4];
        o = o * inv_l;
        int c = 16 * mbc + quad * 4;
        op[(size_t)(c + 0) * T_LEN + t] = o.x;
        op[(size_t)(c + 1) * T_LEN + t] = o.y;
        op[(size_t)(c + 2) * T_LEN + t] = o.z;
        op[(size_t)(c + 3) * T_LEN + t] = o.w;
      }
    }
  }
}

extern "C" void kernel_launch(void* const* d_in, const int* in_sizes, int n_in,
                              void* d_out, int out_size, void* d_ws, size_t ws_size,
                              hipStream_t stream) {
  const float* qkv = (const float*)d_in[0];
  float* out = (float*)d_out;
  dim3 grid(256);   // 256 blocks of 1024 threads (XCD-swizzled in-kernel)
  qkv_attn_mfma<<<grid, 1024, 0, stream>>>(qkv, out);
}